// Round 1
// baseline (24.585 us; speedup 1.0000x reference)
//
#include <hip/hip_runtime.h>

#define NN 1024
#define DD 128

typedef float f32x4 __attribute__((ext_vector_type(4)));
typedef float f32x16 __attribute__((ext_vector_type(16)));
typedef _Float16 f16x8 __attribute__((ext_vector_type(8)));

union H2 { unsigned u; _Float16 h[2]; };

// Kernel 0: xx[i]=|X_i|^2 -> ws[0..1024), yy[j]=|Y_j|^2 -> ws[1024..2048)
// plus zero the d_K_sum region (exactly 512*256 = 131072 threads).
__global__ void norms_zero_k(const float* __restrict__ X, const float* __restrict__ Y,
                             float* __restrict__ ws, float* __restrict__ dk) {
  int ft = blockIdx.x * 256 + threadIdx.x;   // 0..131071
  dk[ft] = 0.0f;
  int wid = ft >> 6;                          // 0..2047: wave per row
  int ln  = ft & 63;
  const float* src = (wid < NN) ? X : Y;
  int row = wid & (NN - 1);
  float a = src[row * DD + ln];
  float b = src[row * DD + 64 + ln];
  float v = a * a + b * b;
  #pragma unroll
  for (int off = 32; off; off >>= 1) v += __shfl_xor(v, off);
  if (ln == 0) ws[wid] = v;
}

// Main kernel: block = (js, ib): i-range ib*32..+32, j-range js*128..+128.
// 4 waves. Wave w: QK^T 32x32 tile (j = w*32..+32, swapped: lane=col=i, regs=j),
// then KY d-tile (d = w*32..+32) over the whole 128-j range via LDS Ks.
__global__ __launch_bounds__(256) void gk_main(const float* __restrict__ X,
                                               const float* __restrict__ Y,
                                               const int* __restrict__ hp,
                                               const float* __restrict__ ws,
                                               float* __restrict__ out) {
  __shared__ __align__(16) _Float16 Xh[32 * 128];    // X tile [i][d], fp16, swizzled
  __shared__ __align__(16) _Float16 Yh[128 * 128];   // Y tile [j][d], fp16, swizzled
  __shared__ __align__(16) _Float16 Yt[128 * 128];   // Y^T tile [d][j], fp16, swizzled
  __shared__ __align__(16) _Float16 Ks[32 * 128];    // K' tile [i][j], fp16-scaled, swizzled
  __shared__ float yys[128];
  __shared__ unsigned msc[32];                       // per-i row max (float bits)
  __shared__ float Sred[32];                         // per-i block row-sum

  const int tid = threadIdx.x;
  const int js  = blockIdx.x;       // 0..7
  const int ib  = blockIdx.y;       // 0..31
  const int lane = tid & 63;
  const int w   = tid >> 6;         // wave 0..3
  const int t   = lane >> 5;        // half-wave 0/1
  const int li  = lane & 31;

  const float fh = (float)hp[0];
  const float inv_h2 = 1.0f / (fh * fh);

  if (tid < 32) { msc[tid] = 0u; Sred[tid] = 0.0f; }
  if (tid < 128) yys[tid] = ws[NN + js * 128 + tid];

  // ---- stage X tile (32x128 f32 -> fp16, granule-swizzled g^=(row&7)) ----
  #pragma unroll
  for (int p = 0; p < 4; ++p) {
    int idx = tid + 256 * p;                 // 0..1023
    int d4 = idx & 31, row = idx >> 5;
    f32x4 v = *(const f32x4*)(X + (ib * 32 + row) * DD + 4 * d4);
    H2 lo, hi;
    lo.h[0] = (_Float16)v.x; lo.h[1] = (_Float16)v.y;
    hi.h[0] = (_Float16)v.z; hi.h[1] = (_Float16)v.w;
    int g = (d4 >> 1) ^ (row & 7);
    unsigned* pdst = (unsigned*)((char*)Xh + row * 256 + g * 16 + (d4 & 1) * 8);
    pdst[0] = lo.u; pdst[1] = hi.u;
  }
  // ---- stage Y tile (128x128): Yh [j][d] and Yt [d][j] ----
  #pragma unroll
  for (int p = 0; p < 8; ++p) {
    int idx = tid + 256 * p;                 // 0..2047
    int d4 = idx & 31, q = idx >> 5;         // rows 2q, 2q+1
    const float* ya = Y + (js * 128 + 2 * q) * DD + 4 * d4;
    f32x4 a = *(const f32x4*)(ya);
    f32x4 b = *(const f32x4*)(ya + DD);
    {
      H2 lo, hi;
      lo.h[0] = (_Float16)a.x; lo.h[1] = (_Float16)a.y;
      hi.h[0] = (_Float16)a.z; hi.h[1] = (_Float16)a.w;
      int row = 2 * q;
      int g = (d4 >> 1) ^ (row & 7);
      unsigned* pdst = (unsigned*)((char*)Yh + row * 256 + g * 16 + (d4 & 1) * 8);
      pdst[0] = lo.u; pdst[1] = hi.u;
    }
    {
      H2 lo, hi;
      lo.h[0] = (_Float16)b.x; lo.h[1] = (_Float16)b.y;
      hi.h[0] = (_Float16)b.z; hi.h[1] = (_Float16)b.w;
      int row = 2 * q + 1;
      int g = (d4 >> 1) ^ (row & 7);
      unsigned* pdst = (unsigned*)((char*)Yh + row * 256 + g * 16 + (d4 & 1) * 8);
      pdst[0] = lo.u; pdst[1] = hi.u;
    }
    #pragma unroll
    for (int c = 0; c < 4; ++c) {
      H2 pk; pk.h[0] = (_Float16)a[c]; pk.h[1] = (_Float16)b[c];  // (Y[2q][d], Y[2q+1][d])
      int d = 4 * d4 + c;
      int g = (q >> 2) ^ ((d >> 2) & 7);
      *(unsigned*)((char*)Yt + d * 256 + g * 16 + (q & 3) * 4) = pk.u;
    }
  }
  __syncthreads();

  // ---- QK^T (swapped: A = Y rows -> D[m=j][n=i]) ----
  f32x16 acc = {};
  const int yrow = w * 32 + li;
  #pragma unroll
  for (int kt = 0; kt < 8; ++kt) {
    int ga = (2 * kt + t) ^ (yrow & 7);
    int gb = (2 * kt + t) ^ (li & 7);
    f16x8 af = *(const f16x8*)(Yh + yrow * 128 + ga * 8);
    f16x8 bf = *(const f16x8*)(Xh + li * 128 + gb * 8);
    acc = __builtin_amdgcn_mfma_f32_32x32x16_f16(af, bf, acc, 0, 0, 0);
  }

  // ---- exp: K = exp(inv_h2*(xy - 0.5*(xx+yy))), clamped <= 1 ----
  const float xxv = ws[ib * 32 + li];
  float K[16];
  float m = 0.0f, sp = 0.0f;
  #pragma unroll
  for (int r = 0; r < 16; ++r) {
    int jl = (r & 3) + 8 * (r >> 2) + 4 * t;          // verified C/D row map
    float yyv = yys[w * 32 + jl];
    float e = fminf((acc[r] - 0.5f * (xxv + yyv)) * inv_h2, 0.0f);
    float kv = exp2f(e * 1.44269504088896341f);
    K[r] = kv; m = fmaxf(m, kv); sp += kv;
  }
  // K store: lane = row i, regs quads are 4 consecutive j -> f32x4 stores
  {
    float* kb = out + (ib * 32 + li) * NN + js * 128 + w * 32 + 4 * t;
    #pragma unroll
    for (int s = 0; s < 4; ++s) {
      f32x4 kv = { K[4 * s], K[4 * s + 1], K[4 * s + 2], K[4 * s + 3] };
      *(f32x4*)(kb + 8 * s) = kv;
    }
  }

  // per-row scale: consistent across both half-waves and all 4 waves
  m = fmaxf(m, __shfl_xor(m, 32));
  if (t == 0) atomicMax(&msc[li], __float_as_uint(m));
  atomicAdd(&Sred[li], sp);
  __syncthreads();

  {
    unsigned ue = (msc[li] >> 23) & 0xffu;
    unsigned se = 266u - ue; if (se > 254u) se = 254u;   // K'max in [2^12, 2^13)
    float scale = __uint_as_float(se << 23);
    #pragma unroll
    for (int c = 0; c < 8; ++c) {
      H2 pk;
      pk.h[0] = (_Float16)(K[2 * c] * scale);
      pk.h[1] = (_Float16)(K[2 * c + 1] * scale);
      int g = (4 * w + (c >> 1)) ^ (li & 7);
      *(unsigned*)((char*)Ks + li * 256 + g * 16 + t * 8 + (c & 1) * 4) = pk.u;
    }
  }
  __syncthreads();

  // ---- K'@Y: wave w owns d-tile [32w, 32w+32), contraction over j=0..127 ----
  f32x16 acc2 = {};
  const int drow = w * 32 + li;
  #pragma unroll
  for (int jt = 0; jt < 8; ++jt) {
    int ga = (2 * jt + t) ^ (li & 7);
    int gb = (2 * jt + t) ^ ((drow >> 2) & 7);
    f16x8 af = *(const f16x8*)(Ks + li * 128 + ga * 8);
    f16x8 bf = *(const f16x8*)(Yt + drow * 128 + gb * 8);
    acc2 = __builtin_amdgcn_mfma_f32_32x32x16_f16(af, bf, acc2, 0, 0, 0);
  }
  float* dk = out + NN * NN;
  #pragma unroll
  for (int r = 0; r < 16; ++r) {
    int il = (r & 3) + 8 * (r >> 2) + 4 * t;
    unsigned ue = (msc[il] >> 23) & 0xffu;
    unsigned se = 266u - ue; if (se > 254u) se = 254u;
    float invs = __uint_as_float((254u - se) << 23);     // 1/scale for row il
    float sred = Sred[il];
    int gi = ib * 32 + il;
    float xv = X[gi * DD + drow];
    float val = (acc2[r] * invs - sred * xv) * inv_h2;
    atomicAdd(dk + gi * DD + drow, val);
  }
}

extern "C" void kernel_launch(void* const* d_in, const int* in_sizes, int n_in,
                              void* d_out, int out_size, void* d_ws, size_t ws_size,
                              hipStream_t stream) {
  const float* X = (const float*)d_in[0];
  const float* Y = (const float*)d_in[1];
  const int*   hp = (const int*)d_in[2];
  float* out = (float*)d_out;
  float* ws  = (float*)d_ws;     // needs 2048 f32 = 8 KB

  // zero dK region + row norms
  hipLaunchKernelGGL(norms_zero_k, dim3(512), dim3(256), 0, stream,
                     X, Y, ws, out + (size_t)NN * NN);
  // fused K + dK partials
  hipLaunchKernelGGL(gk_main, dim3(8, 32), dim3(256), 0, stream,
                     X, Y, hp, ws, out);
}